// Round 5
// baseline (1551.738 us; speedup 1.0000x reference)
//
#include <hip/hip_runtime.h>
#include <hip/hip_bf16.h>

#define BN 4
#define CC 64
#define CR 16
#define HH 96
#define WW 96
#define HWQ (HH*WW)          // 9216
#define HD 48
#define WD 48
#define HWD (HD*WD)          // 2304
#define NKEY 2304
#define KPATCH 144
#define NCOL 2304            // 36*64
#define OH 192
#define OW 192

typedef __bf16 bf16x8 __attribute__((ext_vector_type(8)));
typedef float f32x4 __attribute__((ext_vector_type(4)));

__device__ __forceinline__ void gload_lds16(const void* g, void* l) {
  __builtin_amdgcn_global_load_lds((__attribute__((address_space(1))) void*)g,
                                   (__attribute__((address_space(3))) void*)l,
                                   16, 0, 0);
}

// ---------------- conv1x1 + prelu ----------------
__global__ __launch_bounds__(256) void k_conv1x1_prelu(
    const float* __restrict__ x, const float* __restrict__ w,
    const float* __restrict__ bias, const float* __restrict__ alpha,
    float* __restrict__ out, int O, int HW) {
  int p = blockIdx.x * 256 + threadIdx.x;
  int o = blockIdx.y;
  int b = blockIdx.z;
  if (p >= HW) return;
  const float* xb = x + (size_t)b * CC * HW + p;
  const float* wr = w + o * CC;
  float acc = bias[o];
#pragma unroll 8
  for (int c = 0; c < CC; ++c) acc = fmaf(wr[c], xb[(size_t)c * HW], acc);
  float a = alpha[0];
  out[((size_t)(b * O + o)) * HW + p] = acc >= 0.f ? acc : a * acc;
}

// ---------------- 2x bilinear downsample (== 2x2 average) ----------------
__global__ __launch_bounds__(256) void k_downsample(const float* __restrict__ x,
                                                    float* __restrict__ xd) {
  int idx = blockIdx.x * 256 + threadIdx.x;
  if (idx >= BN * CC * HWD) return;
  int j = idx % WD;
  int t = idx / WD;
  int i = t % HD;
  int bc = t / HD;
  const float* src = x + (size_t)bc * HWQ + (2 * i) * WW + 2 * j;
  xd[idx] = 0.25f * (src[0] + src[1] + src[WW] + src[WW + 1]);
}

// ---------------- per-key reciprocal norms (x10 softmax scale folded) -------
__global__ __launch_bounds__(256) void k_rnorm(const float* __restrict__ kf,
                                               float* __restrict__ rnorm) {
  int idx = blockIdx.x * 256 + threadIdx.x;
  if (idx >= BN * NKEY) return;
  int n = idx % NKEY;
  int b = idx / NKEY;
  int ky = n / WD, kx = n % WD;
  float ss = 0.f;
  for (int c = 0; c < CR; ++c) {
    const float* base = kf + (size_t)(b * CR + c) * HWD;
    for (int i = 0; i < 3; ++i) {
      int y = ky + i - 1;
      if ((unsigned)y >= (unsigned)HD) continue;
      for (int j = 0; j < 3; ++j) {
        int xx = kx + j - 1;
        if ((unsigned)xx >= (unsigned)WD) continue;
        float v = base[y * WD + xx];
        ss += v * v;
      }
    }
  }
  float nrm = fmaxf(sqrtf(ss), 1e-4f);
  rnorm[idx] = 10.f / nrm;
}

// ---------------- build query patches (per sample) ----------------
__global__ __launch_bounds__(256) void k_qpm(const float* __restrict__ q,
                                             float* __restrict__ qpm) {
  int idx = blockIdx.x * 256 + threadIdx.x;
  if (idx >= HWQ * KPATCH) return;
  int k = idx % KPATCH;
  int p = idx / KPATCH;
  int c = k / 9, r = k % 9;
  int i = r / 3, j = r % 3;
  int y = p / WW, x = p % WW;
  int yy = y + i - 1, xx = x + j - 1;
  float v = 0.f;
  if ((unsigned)yy < (unsigned)HH && (unsigned)xx < (unsigned)WW)
    v = q[(size_t)c * HWQ + yy * WW + xx];
  qpm[idx] = v;
}

// ---------------- build key patches scaled by 10/norm (per sample) ----------
__global__ __launch_bounds__(256) void k_kpm(const float* __restrict__ kf,
                                             const float* __restrict__ rn,
                                             float* __restrict__ kpm) {
  int idx = blockIdx.x * 256 + threadIdx.x;
  if (idx >= NKEY * KPATCH) return;
  int k = idx % KPATCH;
  int n = idx / KPATCH;
  int c = k / 9, r = k % 9;
  int i = r / 3, j = r % 3;
  int ky = n / WD, kx = n % WD;
  int yy = ky + i - 1, xx = kx + j - 1;
  float v = 0.f;
  if ((unsigned)yy < (unsigned)HD && (unsigned)xx < (unsigned)WD)
    v = kf[(size_t)c * HWD + yy * WD + xx];
  kpm[idx] = rn[n] * v;
}

// ---------------- scores GEMM (f32): scT[p][n] = qpm[p,:]·kpm[n,:] ---------
__global__ __launch_bounds__(256) void k_scores(const float* __restrict__ qpm,
                                                const float* __restrict__ kpm,
                                                float* __restrict__ scT) {
  __shared__ float qs[64 * 49];
  __shared__ float ks[64 * 49];
  int m0 = blockIdx.x * 64, n0 = blockIdx.y * 64;
  int tid = threadIdx.x;
  int ti = tid >> 4, tj = tid & 15;
  float acc[4][4] = {};
  for (int kc = 0; kc < 3; ++kc) {
    __syncthreads();
    for (int idx = tid; idx < 64 * 48; idx += 256) {
      int r = idx / 48, k = idx % 48;
      qs[r * 49 + k] = qpm[(size_t)(m0 + r) * KPATCH + kc * 48 + k];
      ks[r * 49 + k] = kpm[(size_t)(n0 + r) * KPATCH + kc * 48 + k];
    }
    __syncthreads();
    for (int k = 0; k < 48; ++k) {
      float qa[4], kb[4];
#pragma unroll
      for (int a = 0; a < 4; ++a) qa[a] = qs[(ti * 4 + a) * 49 + k];
#pragma unroll
      for (int bb = 0; bb < 4; ++bb) kb[bb] = ks[(tj * 4 + bb) * 49 + k];
#pragma unroll
      for (int a = 0; a < 4; ++a)
#pragma unroll
        for (int bb = 0; bb < 4; ++bb) acc[a][bb] = fmaf(qa[a], kb[bb], acc[a][bb]);
    }
  }
  for (int a = 0; a < 4; ++a)
    for (int bb = 0; bb < 4; ++bb)
      scT[(size_t)(m0 + ti * 4 + a) * NKEY + n0 + tj * 4 + bb] = acc[a][bb];
}

// ---------------- row softmax over 2304 keys -> bf16 ----------------
__global__ __launch_bounds__(256) void k_softmax(const float* __restrict__ scT,
                                                 __hip_bfloat16* __restrict__ attT) {
  int p = blockIdx.x;
  int tid = threadIdx.x;
  const float* row = scT + (size_t)p * NKEY;
  float v[9];
  float mx = -1e30f;
#pragma unroll
  for (int t = 0; t < 9; ++t) {
    v[t] = row[tid + t * 256];
    mx = fmaxf(mx, v[t]);
  }
  for (int off = 32; off; off >>= 1) mx = fmaxf(mx, __shfl_xor(mx, off));
  __shared__ float red[4];
  __shared__ float red2[4];
  if ((tid & 63) == 0) red[tid >> 6] = mx;
  __syncthreads();
  mx = fmaxf(fmaxf(red[0], red[1]), fmaxf(red[2], red[3]));
  float s = 0.f;
#pragma unroll
  for (int t = 0; t < 9; ++t) {
    v[t] = __expf(v[t] - mx);
    s += v[t];
  }
  for (int off = 32; off; off >>= 1) s += __shfl_xor(s, off);
  if ((tid & 63) == 0) red2[tid >> 6] = s;
  __syncthreads();
  s = red2[0] + red2[1] + red2[2] + red2[3];
  float inv = 1.f / s;
#pragma unroll
  for (int t = 0; t < 9; ++t)
    attT[(size_t)p * NKEY + tid + t * 256] = __float2bfloat16(v[t] * inv);
}

// ---------------- build value patches apT[col][n], col=(i*6+j)*64+o --------
__global__ __launch_bounds__(256) void k_apT(const float* __restrict__ asmb,
                                             __hip_bfloat16* __restrict__ apT) {
  int idx = blockIdx.x * 256 + threadIdx.x;
  if (idx >= NCOL * NKEY) return;
  int n = idx % NKEY;
  int col = idx / NKEY;
  int o = col & 63;
  int ij = col >> 6;
  int i = ij / 6, j = ij % 6;
  int ky = n / WD, kx = n % WD;
  int y = 2 * ky + i - 2, x = 2 * kx + j - 2;
  float v = 0.f;
  if ((unsigned)y < (unsigned)HH && (unsigned)x < (unsigned)WW)
    v = asmb[(size_t)o * HWQ + y * WW + x];
  apT[idx] = __float2bfloat16(v);
}

// ---------------- AV GEMM bf16 MFMA: V[M=9216][N=2304], K=2304 --------------
__global__ __launch_bounds__(256) void k_av(const __hip_bfloat16* __restrict__ A,
                                            const __hip_bfloat16* __restrict__ Bm,
                                            float* __restrict__ V) {
  __shared__ __align__(1024) __hip_bfloat16 Ash[128 * 32];
  __shared__ __align__(1024) __hip_bfloat16 Bsh[128 * 32];
  const int m0 = blockIdx.x * 128, n0 = blockIdx.y * 128;
  const int tid = threadIdx.x;
  const int w = tid >> 6, l = tid & 63;
  const int wr = w >> 1, wc = w & 1;
  const int KDIM = 2304;
  f32x4 acc[4][4] = {};
  for (int kt = 0; kt < KDIM / 32; ++kt) {
#pragma unroll
    for (int q2 = 0; q2 < 2; ++q2) {
      int c = w * 2 + q2;
      gload_lds16(
          (const char*)A + ((size_t)(m0 + 16 * c + (l >> 2)) * KDIM + (size_t)kt * 32 + (l & 3) * 8) * 2,
          (char*)Ash + c * 1024);
      gload_lds16(
          (const char*)Bm + ((size_t)(n0 + 16 * c + (l >> 2)) * KDIM + (size_t)kt * 32 + (l & 3) * 8) * 2,
          (char*)Bsh + c * 1024);
    }
    __syncthreads();
    const char* Ab = (const char*)Ash + (wr * 64 + (l & 15)) * 64 + (l >> 4) * 16;
    const char* Bb = (const char*)Bsh + (wc * 64 + (l & 15)) * 64 + (l >> 4) * 16;
    bf16x8 af[4], bfv[4];
#pragma unroll
    for (int mi = 0; mi < 4; ++mi) af[mi] = *(const bf16x8*)(Ab + mi * 16 * 64);
#pragma unroll
    for (int ni = 0; ni < 4; ++ni) bfv[ni] = *(const bf16x8*)(Bb + ni * 16 * 64);
#pragma unroll
    for (int mi = 0; mi < 4; ++mi)
#pragma unroll
      for (int ni = 0; ni < 4; ++ni)
        acc[mi][ni] = __builtin_amdgcn_mfma_f32_16x16x32_bf16(af[mi], bfv[ni], acc[mi][ni], 0, 0, 0);
    __syncthreads();
  }
#pragma unroll
  for (int mi = 0; mi < 4; ++mi) {
    int mrow = m0 + wr * 64 + mi * 16 + (l >> 4) * 4;
#pragma unroll
    for (int ni = 0; ni < 4; ++ni) {
      int ncol = n0 + wc * 64 + ni * 16 + (l & 15);
#pragma unroll
      for (int r = 0; r < 4; ++r)
        V[(size_t)(mrow + r) * NCOL + ncol] = acc[mi][ni][r];
    }
  }
}

// ---------------- gather (transposed conv collapse), /6 ----------------
__global__ __launch_bounds__(256) void k_gather(const float* __restrict__ V,
                                                float* __restrict__ out) {
  int tid = threadIdx.x;
  int o = tid & 63;
  int X = blockIdx.x * 4 + (tid >> 6);
  int Y = blockIdx.y;
  int y0 = (Y >= 3) ? ((Y - 2) >> 1) : 0;
  int y1 = (Y + 2) >> 1;
  if (y1 > HH - 1) y1 = HH - 1;
  int x0 = (X >= 3) ? ((X - 2) >> 1) : 0;
  int x1 = (X + 2) >> 1;
  if (x1 > WW - 1) x1 = WW - 1;
  float acc = 0.f;
  for (int y = y0; y <= y1; ++y) {
    int i = Y - 2 * y + 2;
    for (int x = x0; x <= x1; ++x) {
      int j = X - 2 * x + 2;
      acc += V[(size_t)(y * WW + x) * NCOL + (i * 6 + j) * 64 + o];
    }
  }
  out[(size_t)o * (OH * OW) + Y * OW + X] = acc * (1.f / 6.f);
}

extern "C" void kernel_launch(void* const* d_in, const int* in_sizes, int n_in,
                              void* d_out, int out_size, void* d_ws, size_t ws_size,
                              hipStream_t stream) {
  const float* x  = (const float*)d_in[0];
  const float* wa = (const float*)d_in[1];
  const float* ba = (const float*)d_in[2];
  const float* aa = (const float*)d_in[3];
  const float* w1 = (const float*)d_in[4];
  const float* b1 = (const float*)d_in[5];
  const float* a1 = (const float*)d_in[6];
  const float* w2 = (const float*)d_in[7];
  const float* b2 = (const float*)d_in[8];
  const float* a2 = (const float*)d_in[9];
  float* out = (float*)d_out;

  char* ws = (char*)d_ws;
  size_t off = 0;
  auto alloc = [&](size_t bytes) {
    char* p = ws + off;
    off += (bytes + 255) & ~(size_t)255;
    return p;
  };
  float* asm_b  = (float*)alloc((size_t)BN * CC * HWQ * 4);   // 9.4 MB
  float* q_b    = (float*)alloc((size_t)BN * CR * HWQ * 4);   // 2.4 MB
  float* xd_b   = (float*)alloc((size_t)BN * CC * HWD * 4);   // 2.4 MB
  float* kf_b   = (float*)alloc((size_t)BN * CR * HWD * 4);   // 0.6 MB
  float* rn_b   = (float*)alloc((size_t)BN * NKEY * 4);
  float* qpm_b  = (float*)alloc((size_t)HWQ * KPATCH * 4);    // 5.3 MB
  float* kpm_b  = (float*)alloc((size_t)NKEY * KPATCH * 4);   // 1.3 MB
  float* scV_b  = (float*)alloc((size_t)HWQ * NKEY * 4);      // 85 MB (scores, then V)
  __hip_bfloat16* attT_b = (__hip_bfloat16*)alloc((size_t)HWQ * NKEY * 2);  // 42.5 MB
  __hip_bfloat16* apT_b  = (__hip_bfloat16*)alloc((size_t)NCOL * NKEY * 2); // 10.6 MB

  // shared preprocessing (all samples at once)
  k_conv1x1_prelu<<<dim3(HWQ / 256, CC, BN), 256, 0, stream>>>(x, wa, ba, aa, asm_b, CC, HWQ);
  k_conv1x1_prelu<<<dim3(HWQ / 256, CR, BN), 256, 0, stream>>>(x, w1, b1, a1, q_b, CR, HWQ);
  k_downsample<<<(BN * CC * HWD + 255) / 256, 256, 0, stream>>>(x, xd_b);
  k_conv1x1_prelu<<<dim3(HWD / 256, CR, BN), 256, 0, stream>>>(xd_b, w2, b2, a2, kf_b, CR, HWD);
  k_rnorm<<<(BN * NKEY + 255) / 256, 256, 0, stream>>>(kf_b, rn_b);

  for (int b = 0; b < BN; ++b) {
    const float* qb   = q_b  + (size_t)b * CR * HWQ;
    const float* kfb  = kf_b + (size_t)b * CR * HWD;
    const float* rnb  = rn_b + (size_t)b * NKEY;
    const float* asmb = asm_b + (size_t)b * CC * HWQ;
    float* outb = out + (size_t)b * CC * OH * OW;

    k_qpm<<<(HWQ * KPATCH + 255) / 256, 256, 0, stream>>>(qb, qpm_b);
    k_kpm<<<(NKEY * KPATCH + 255) / 256, 256, 0, stream>>>(kfb, rnb, kpm_b);
    k_scores<<<dim3(HWQ / 64, NKEY / 64), 256, 0, stream>>>(qpm_b, kpm_b, scV_b);
    k_softmax<<<HWQ, 256, 0, stream>>>(scV_b, attT_b);
    k_apT<<<(NCOL * NKEY + 255) / 256, 256, 0, stream>>>(asmb, apT_b);
    k_av<<<dim3(HWQ / 128, NCOL / 128), 256, 0, stream>>>(attT_b, apT_b, scV_b);
    k_gather<<<dim3(OW / 4, OH), 256, 0, stream>>>(scV_b, outb);
  }
}

// Round 10
// 1192.486 us; speedup vs baseline: 1.3013x; 1.3013x over previous
//
#include <hip/hip_runtime.h>
#include <hip/hip_bf16.h>

#define BN 4
#define CC 64
#define CR 16
#define HH 96
#define WW 96
#define HWQ (HH*WW)          // 9216
#define HD 48
#define WD 48
#define HWD (HD*WD)          // 2304
#define NKEY 2304
#define KPATCH 144
#define KSC 448              // split-K' = 3*144 padded to 448 (mult of 32)
#define NCOL 2304            // 36*64
#define OH 192
#define OW 192

typedef __bf16 bf16x8 __attribute__((ext_vector_type(8)));
typedef float f32x4 __attribute__((ext_vector_type(4)));

__device__ __forceinline__ void gload_lds16(const void* g, void* l) {
  __builtin_amdgcn_global_load_lds((__attribute__((address_space(1))) void*)g,
                                   (__attribute__((address_space(3))) void*)l,
                                   16, 0, 0);
}

// ---------------- conv1x1 + prelu ----------------
__global__ __launch_bounds__(256) void k_conv1x1_prelu(
    const float* __restrict__ x, const float* __restrict__ w,
    const float* __restrict__ bias, const float* __restrict__ alpha,
    float* __restrict__ out, int O, int HW) {
  int p = blockIdx.x * 256 + threadIdx.x;
  int o = blockIdx.y;
  int b = blockIdx.z;
  if (p >= HW) return;
  const float* xb = x + (size_t)b * CC * HW + p;
  const float* wr = w + o * CC;
  float acc = bias[o];
#pragma unroll 8
  for (int c = 0; c < CC; ++c) acc = fmaf(wr[c], xb[(size_t)c * HW], acc);
  float a = alpha[0];
  out[((size_t)(b * O + o)) * HW + p] = acc >= 0.f ? acc : a * acc;
}

// ---------------- 2x bilinear downsample (== 2x2 average) ----------------
__global__ __launch_bounds__(256) void k_downsample(const float* __restrict__ x,
                                                    float* __restrict__ xd) {
  int idx = blockIdx.x * 256 + threadIdx.x;
  if (idx >= BN * CC * HWD) return;
  int j = idx % WD;
  int t = idx / WD;
  int i = t % HD;
  int bc = t / HD;
  const float* src = x + (size_t)bc * HWQ + (2 * i) * WW + 2 * j;
  xd[idx] = 0.25f * (src[0] + src[1] + src[WW] + src[WW + 1]);
}

// ---------------- per-key reciprocal norms (x10 softmax scale folded) -------
__global__ __launch_bounds__(256) void k_rnorm(const float* __restrict__ kf,
                                               float* __restrict__ rnorm) {
  int idx = blockIdx.x * 256 + threadIdx.x;
  if (idx >= BN * NKEY) return;
  int n = idx % NKEY;
  int b = idx / NKEY;
  int ky = n / WD, kx = n % WD;
  float ss = 0.f;
  for (int c = 0; c < CR; ++c) {
    const float* base = kf + (size_t)(b * CR + c) * HWD;
    for (int i = 0; i < 3; ++i) {
      int y = ky + i - 1;
      if ((unsigned)y >= (unsigned)HD) continue;
      for (int j = 0; j < 3; ++j) {
        int xx = kx + j - 1;
        if ((unsigned)xx >= (unsigned)WD) continue;
        float v = base[y * WD + xx];
        ss += v * v;
      }
    }
  }
  float nrm = fmaxf(sqrtf(ss), 1e-4f);
  rnorm[idx] = 10.f / nrm;
}

// ---- build bf16 hi/lo split query patches: [HWQ][KSC]
// layout per row: [0,144)=hi, [144,288)=lo, [288,432)=hi, [432,448)=0
__global__ __launch_bounds__(256) void k_qpm2(const float* __restrict__ q,
                                              __hip_bfloat16* __restrict__ qpm2) {
  int idx = blockIdx.x * 256 + threadIdx.x;
  if (idx >= HWQ * KPATCH) return;
  int k = idx % KPATCH;
  int p = idx / KPATCH;
  int c = k / 9, r = k % 9;
  int i = r / 3, j = r % 3;
  int y = p / WW, x = p % WW;
  int yy = y + i - 1, xx = x + j - 1;
  float v = 0.f;
  if ((unsigned)yy < (unsigned)HH && (unsigned)xx < (unsigned)WW)
    v = q[(size_t)c * HWQ + yy * WW + xx];
  __hip_bfloat16 hi = __float2bfloat16(v);
  __hip_bfloat16 lo = __float2bfloat16(v - __bfloat162float(hi));
  __hip_bfloat16* row = qpm2 + (size_t)p * KSC;
  row[k] = hi;
  row[KPATCH + k] = lo;
  row[2 * KPATCH + k] = hi;
  if (k < KSC - 3 * KPATCH) row[3 * KPATCH + k] = __float2bfloat16(0.f);
}

// ---- build bf16 hi/lo split key patches scaled by 10/norm: [NKEY][KSC]
// layout per row: [0,144)=hi, [144,288)=hi, [288,432)=lo, [432,448)=0
__global__ __launch_bounds__(256) void k_kpm2(const float* __restrict__ kf,
                                              const float* __restrict__ rn,
                                              __hip_bfloat16* __restrict__ kpm2) {
  int idx = blockIdx.x * 256 + threadIdx.x;
  if (idx >= NKEY * KPATCH) return;
  int k = idx % KPATCH;
  int n = idx / KPATCH;
  int c = k / 9, r = k % 9;
  int i = r / 3, j = r % 3;
  int ky = n / WD, kx = n % WD;
  int yy = ky + i - 1, xx = kx + j - 1;
  float v = 0.f;
  if ((unsigned)yy < (unsigned)HD && (unsigned)xx < (unsigned)WD)
    v = kf[(size_t)c * HWD + yy * WD + xx];
  v *= rn[n];
  __hip_bfloat16 hi = __float2bfloat16(v);
  __hip_bfloat16 lo = __float2bfloat16(v - __bfloat162float(hi));
  __hip_bfloat16* row = kpm2 + (size_t)n * KSC;
  row[k] = hi;
  row[KPATCH + k] = hi;
  row[2 * KPATCH + k] = lo;
  if (k < KSC - 3 * KPATCH) row[3 * KPATCH + k] = __float2bfloat16(0.f);
}

// ---------------- bf16 MFMA GEMM (B^T): D[m][n] = sum_k A[m][k] B[n][k] -----
// M rows = 128*gridDim.x, N cols = 128*gridDim.y, row strides = KDIM (A,B), NCOL (D)
template <int KDIM>
__global__ __launch_bounds__(256) void k_gemm_bt(const __hip_bfloat16* __restrict__ A,
                                                 const __hip_bfloat16* __restrict__ Bm,
                                                 float* __restrict__ D) {
  __shared__ __align__(1024) __hip_bfloat16 Ash[128 * 32];
  __shared__ __align__(1024) __hip_bfloat16 Bsh[128 * 32];
  const int m0 = blockIdx.x * 128, n0 = blockIdx.y * 128;
  const int tid = threadIdx.x;
  const int w = tid >> 6, l = tid & 63;
  const int wr = w >> 1, wc = w & 1;
  f32x4 acc[4][4] = {};
  for (int kt = 0; kt < KDIM / 32; ++kt) {
#pragma unroll
    for (int q2 = 0; q2 < 2; ++q2) {
      int c = w * 2 + q2;
      gload_lds16(
          (const char*)A + ((size_t)(m0 + 16 * c + (l >> 2)) * KDIM + (size_t)kt * 32 + (l & 3) * 8) * 2,
          (char*)Ash + c * 1024);
      gload_lds16(
          (const char*)Bm + ((size_t)(n0 + 16 * c + (l >> 2)) * KDIM + (size_t)kt * 32 + (l & 3) * 8) * 2,
          (char*)Bsh + c * 1024);
    }
    __syncthreads();
    const char* Ab = (const char*)Ash + (wr * 64 + (l & 15)) * 64 + (l >> 4) * 16;
    const char* Bb = (const char*)Bsh + (wc * 64 + (l & 15)) * 64 + (l >> 4) * 16;
    bf16x8 af[4], bfv[4];
#pragma unroll
    for (int mi = 0; mi < 4; ++mi) af[mi] = *(const bf16x8*)(Ab + mi * 16 * 64);
#pragma unroll
    for (int ni = 0; ni < 4; ++ni) bfv[ni] = *(const bf16x8*)(Bb + ni * 16 * 64);
#pragma unroll
    for (int mi = 0; mi < 4; ++mi)
#pragma unroll
      for (int ni = 0; ni < 4; ++ni)
        acc[mi][ni] = __builtin_amdgcn_mfma_f32_16x16x32_bf16(af[mi], bfv[ni], acc[mi][ni], 0, 0, 0);
    __syncthreads();
  }
#pragma unroll
  for (int mi = 0; mi < 4; ++mi) {
    int mrow = m0 + wr * 64 + mi * 16 + (l >> 4) * 4;
#pragma unroll
    for (int ni = 0; ni < 4; ++ni) {
      int ncol = n0 + wc * 64 + ni * 16 + (l & 15);
#pragma unroll
      for (int r = 0; r < 4; ++r)
        D[(size_t)(mrow + r) * NCOL + ncol] = acc[mi][ni][r];
    }
  }
}

// ---------------- row softmax over 2304 keys -> bf16 ----------------
__global__ __launch_bounds__(256) void k_softmax(const float* __restrict__ scT,
                                                 __hip_bfloat16* __restrict__ attT) {
  int p = blockIdx.x;
  int tid = threadIdx.x;
  const float* row = scT + (size_t)p * NKEY;
  float v[9];
  float mx = -1e30f;
#pragma unroll
  for (int t = 0; t < 9; ++t) {
    v[t] = row[tid + t * 256];
    mx = fmaxf(mx, v[t]);
  }
  for (int off = 32; off; off >>= 1) mx = fmaxf(mx, __shfl_xor(mx, off));
  __shared__ float red[4];
  __shared__ float red2[4];
  if ((tid & 63) == 0) red[tid >> 6] = mx;
  __syncthreads();
  mx = fmaxf(fmaxf(red[0], red[1]), fmaxf(red[2], red[3]));
  float s = 0.f;
#pragma unroll
  for (int t = 0; t < 9; ++t) {
    v[t] = __expf(v[t] - mx);
    s += v[t];
  }
  for (int off = 32; off; off >>= 1) s += __shfl_xor(s, off);
  if ((tid & 63) == 0) red2[tid >> 6] = s;
  __syncthreads();
  s = red2[0] + red2[1] + red2[2] + red2[3];
  float inv = 1.f / s;
#pragma unroll
  for (int t = 0; t < 9; ++t)
    attT[(size_t)p * NKEY + tid + t * 256] = __float2bfloat16(v[t] * inv);
}

// ---------------- build value patches apT[col][n], col=(i*6+j)*64+o --------
__global__ __launch_bounds__(256) void k_apT(const float* __restrict__ asmb,
                                             __hip_bfloat16* __restrict__ apT) {
  int idx = blockIdx.x * 256 + threadIdx.x;
  if (idx >= NCOL * NKEY) return;
  int n = idx % NKEY;
  int col = idx / NKEY;
  int o = col & 63;
  int ij = col >> 6;
  int i = ij / 6, j = ij % 6;
  int ky = n / WD, kx = n % WD;
  int y = 2 * ky + i - 2, x = 2 * kx + j - 2;
  float v = 0.f;
  if ((unsigned)y < (unsigned)HH && (unsigned)x < (unsigned)WW)
    v = asmb[(size_t)o * HWQ + y * WW + x];
  apT[idx] = __float2bfloat16(v);
}

// ---------------- gather (transposed conv collapse), /6 ----------------
__global__ __launch_bounds__(256) void k_gather(const float* __restrict__ V,
                                                float* __restrict__ out) {
  int tid = threadIdx.x;
  int o = tid & 63;
  int X = blockIdx.x * 4 + (tid >> 6);
  int Y = blockIdx.y;
  int y0 = (Y >= 3) ? ((Y - 2) >> 1) : 0;
  int y1 = (Y + 2) >> 1;
  if (y1 > HH - 1) y1 = HH - 1;
  int x0 = (X >= 3) ? ((X - 2) >> 1) : 0;
  int x1 = (X + 2) >> 1;
  if (x1 > WW - 1) x1 = WW - 1;
  float acc = 0.f;
  for (int y = y0; y <= y1; ++y) {
    int i = Y - 2 * y + 2;
    for (int x = x0; x <= x1; ++x) {
      int j = X - 2 * x + 2;
      acc += V[(size_t)(y * WW + x) * NCOL + (i * 6 + j) * 64 + o];
    }
  }
  out[(size_t)o * (OH * OW) + Y * OW + X] = acc * (1.f / 6.f);
}

extern "C" void kernel_launch(void* const* d_in, const int* in_sizes, int n_in,
                              void* d_out, int out_size, void* d_ws, size_t ws_size,
                              hipStream_t stream) {
  const float* x  = (const float*)d_in[0];
  const float* wa = (const float*)d_in[1];
  const float* ba = (const float*)d_in[2];
  const float* aa = (const float*)d_in[3];
  const float* w1 = (const float*)d_in[4];
  const float* b1 = (const float*)d_in[5];
  const float* a1 = (const float*)d_in[6];
  const float* w2 = (const float*)d_in[7];
  const float* b2 = (const float*)d_in[8];
  const float* a2 = (const float*)d_in[9];
  float* out = (float*)d_out;

  char* ws = (char*)d_ws;
  size_t off = 0;
  auto alloc = [&](size_t bytes) {
    char* p = ws + off;
    off += (bytes + 255) & ~(size_t)255;
    return p;
  };
  float* asm_b  = (float*)alloc((size_t)BN * CC * HWQ * 4);   // 9.4 MB
  float* q_b    = (float*)alloc((size_t)BN * CR * HWQ * 4);   // 2.4 MB
  float* xd_b   = (float*)alloc((size_t)BN * CC * HWD * 4);   // 2.4 MB
  float* kf_b   = (float*)alloc((size_t)BN * CR * HWD * 4);   // 0.6 MB
  float* rn_b   = (float*)alloc((size_t)BN * NKEY * 4);
  __hip_bfloat16* qpm2_b = (__hip_bfloat16*)alloc((size_t)HWQ * KSC * 2);   // 8.3 MB
  __hip_bfloat16* kpm2_b = (__hip_bfloat16*)alloc((size_t)NKEY * KSC * 2);  // 2.1 MB
  float* scV_b  = (float*)alloc((size_t)HWQ * NKEY * 4);      // 85 MB (scores, then V)
  __hip_bfloat16* attT_b = (__hip_bfloat16*)alloc((size_t)HWQ * NKEY * 2);  // 42.5 MB
  __hip_bfloat16* apT_b  = (__hip_bfloat16*)alloc((size_t)NCOL * NKEY * 2); // 10.6 MB

  // shared preprocessing (all samples at once)
  k_conv1x1_prelu<<<dim3(HWQ / 256, CC, BN), 256, 0, stream>>>(x, wa, ba, aa, asm_b, CC, HWQ);
  k_conv1x1_prelu<<<dim3(HWQ / 256, CR, BN), 256, 0, stream>>>(x, w1, b1, a1, q_b, CR, HWQ);
  k_downsample<<<(BN * CC * HWD + 255) / 256, 256, 0, stream>>>(x, xd_b);
  k_conv1x1_prelu<<<dim3(HWD / 256, CR, BN), 256, 0, stream>>>(xd_b, w2, b2, a2, kf_b, CR, HWD);
  k_rnorm<<<(BN * NKEY + 255) / 256, 256, 0, stream>>>(kf_b, rn_b);

  for (int b = 0; b < BN; ++b) {
    const float* qb   = q_b  + (size_t)b * CR * HWQ;
    const float* kfb  = kf_b + (size_t)b * CR * HWD;
    const float* rnb  = rn_b + (size_t)b * NKEY;
    const float* asmb = asm_b + (size_t)b * CC * HWQ;
    float* outb = out + (size_t)b * CC * OH * OW;

    k_qpm2<<<(HWQ * KPATCH + 255) / 256, 256, 0, stream>>>(qb, qpm2_b);
    k_kpm2<<<(NKEY * KPATCH + 255) / 256, 256, 0, stream>>>(kfb, rnb, kpm2_b);
    k_gemm_bt<KSC><<<dim3(HWQ / 128, NKEY / 128), 256, 0, stream>>>(qpm2_b, kpm2_b, scV_b);
    k_softmax<<<HWQ, 256, 0, stream>>>(scV_b, attT_b);
    k_apT<<<(NCOL * NKEY + 255) / 256, 256, 0, stream>>>(asmb, apT_b);
    k_gemm_bt<NKEY><<<dim3(HWQ / 128, NCOL / 128), 256, 0, stream>>>(attT_b, apT_b, scV_b);
    k_gather<<<dim3(OW / 4, OH), 256, 0, stream>>>(scV_b, outb);
  }
}

// Round 13
// 1041.623 us; speedup vs baseline: 1.4897x; 1.1448x over previous
//
#include <hip/hip_runtime.h>
#include <hip/hip_bf16.h>

#define BN 4
#define CC 64
#define CR 16
#define HH 96
#define WW 96
#define HWQ (HH*WW)          // 9216
#define HD 48
#define WD 48
#define HWD (HD*WD)          // 2304
#define NKEY 2304
#define KPATCH 144
#define KSC 448              // split-K' = 3*144 padded to 448 (mult of 32)
#define NCOL 2304            // 36*64
#define OH 192
#define OW 192

typedef __bf16 bf16x8 __attribute__((ext_vector_type(8)));
typedef float f32x4 __attribute__((ext_vector_type(4)));
typedef short s16x4 __attribute__((ext_vector_type(4)));

__device__ __forceinline__ void gload_lds16(const void* g, void* l) {
  __builtin_amdgcn_global_load_lds((__attribute__((address_space(1))) void*)g,
                                   (__attribute__((address_space(3))) void*)l,
                                   16, 0, 0);
}

// ---------------- conv1x1 + prelu ----------------
__global__ __launch_bounds__(256) void k_conv1x1_prelu(
    const float* __restrict__ x, const float* __restrict__ w,
    const float* __restrict__ bias, const float* __restrict__ alpha,
    float* __restrict__ out, int O, int HW) {
  int p = blockIdx.x * 256 + threadIdx.x;
  int o = blockIdx.y;
  int b = blockIdx.z;
  if (p >= HW) return;
  const float* xb = x + (size_t)b * CC * HW + p;
  const float* wr = w + o * CC;
  float acc = bias[o];
#pragma unroll 8
  for (int c = 0; c < CC; ++c) acc = fmaf(wr[c], xb[(size_t)c * HW], acc);
  float a = alpha[0];
  out[((size_t)(b * O + o)) * HW + p] = acc >= 0.f ? acc : a * acc;
}

// ---------------- 2x bilinear downsample (== 2x2 average) ----------------
__global__ __launch_bounds__(256) void k_downsample(const float* __restrict__ x,
                                                    float* __restrict__ xd) {
  int idx = blockIdx.x * 256 + threadIdx.x;
  if (idx >= BN * CC * HWD) return;
  int j = idx % WD;
  int t = idx / WD;
  int i = t % HD;
  int bc = t / HD;
  const float* src = x + (size_t)bc * HWQ + (2 * i) * WW + 2 * j;
  xd[idx] = 0.25f * (src[0] + src[1] + src[WW] + src[WW + 1]);
}

// ---------------- per-key reciprocal norms (x10 softmax scale folded) -------
__global__ __launch_bounds__(256) void k_rnorm(const float* __restrict__ kf,
                                               float* __restrict__ rnorm) {
  int idx = blockIdx.x * 256 + threadIdx.x;
  if (idx >= BN * NKEY) return;
  int n = idx % NKEY;
  int b = idx / NKEY;
  int ky = n / WD, kx = n % WD;
  float ss = 0.f;
  for (int c = 0; c < CR; ++c) {
    const float* base = kf + (size_t)(b * CR + c) * HWD;
    for (int i = 0; i < 3; ++i) {
      int y = ky + i - 1;
      if ((unsigned)y >= (unsigned)HD) continue;
      for (int j = 0; j < 3; ++j) {
        int xx = kx + j - 1;
        if ((unsigned)xx >= (unsigned)WD) continue;
        float v = base[y * WD + xx];
        ss += v * v;
      }
    }
  }
  float nrm = fmaxf(sqrtf(ss), 1e-4f);
  rnorm[idx] = 10.f / nrm;
}

// ---- build bf16 hi/lo split query patches: [HWQ][KSC]
// layout per row: [0,144)=hi, [144,288)=lo, [288,432)=hi, [432,448)=0
__global__ __launch_bounds__(256) void k_qpm2(const float* __restrict__ q,
                                              __hip_bfloat16* __restrict__ qpm2) {
  int idx = blockIdx.x * 256 + threadIdx.x;
  if (idx >= HWQ * KPATCH) return;
  int k = idx % KPATCH;
  int p = idx / KPATCH;
  int c = k / 9, r = k % 9;
  int i = r / 3, j = r % 3;
  int y = p / WW, x = p % WW;
  int yy = y + i - 1, xx = x + j - 1;
  float v = 0.f;
  if ((unsigned)yy < (unsigned)HH && (unsigned)xx < (unsigned)WW)
    v = q[(size_t)c * HWQ + yy * WW + xx];
  __hip_bfloat16 hi = __float2bfloat16(v);
  __hip_bfloat16 lo = __float2bfloat16(v - __bfloat162float(hi));
  __hip_bfloat16* row = qpm2 + (size_t)p * KSC;
  row[k] = hi;
  row[KPATCH + k] = lo;
  row[2 * KPATCH + k] = hi;
  if (k < KSC - 3 * KPATCH) row[3 * KPATCH + k] = __float2bfloat16(0.f);
}

// ---- build bf16 hi/lo split key patches scaled by 10/norm: [NKEY][KSC]
// layout per row: [0,144)=hi, [144,288)=hi, [288,432)=lo, [432,448)=0
__global__ __launch_bounds__(256) void k_kpm2(const float* __restrict__ kf,
                                              const float* __restrict__ rn,
                                              __hip_bfloat16* __restrict__ kpm2) {
  int idx = blockIdx.x * 256 + threadIdx.x;
  if (idx >= NKEY * KPATCH) return;
  int k = idx % KPATCH;
  int n = idx / KPATCH;
  int c = k / 9, r = k % 9;
  int i = r / 3, j = r % 3;
  int ky = n / WD, kx = n % WD;
  int yy = ky + i - 1, xx = kx + j - 1;
  float v = 0.f;
  if ((unsigned)yy < (unsigned)HD && (unsigned)xx < (unsigned)WD)
    v = kf[(size_t)c * HWD + yy * WD + xx];
  v *= rn[n];
  __hip_bfloat16 hi = __float2bfloat16(v);
  __hip_bfloat16 lo = __float2bfloat16(v - __bfloat162float(hi));
  __hip_bfloat16* row = kpm2 + (size_t)n * KSC;
  row[k] = hi;
  row[KPATCH + k] = hi;
  row[2 * KPATCH + k] = lo;
  if (k < KSC - 3 * KPATCH) row[3 * KPATCH + k] = __float2bfloat16(0.f);
}

// ---------------- bf16 MFMA GEMM (B^T): D[m][n] = sum_k A[m][k] B[n][k] -----
// M rows = 128*gridDim.x, N cols = 128*gridDim.y, row strides = KDIM (A,B), NCOL (D)
// OUT_BF16: write D as bf16 (AV path) else f32 (scores path)
template <int KDIM, bool OUT_BF16>
__global__ __launch_bounds__(256) void k_gemm_bt(const __hip_bfloat16* __restrict__ A,
                                                 const __hip_bfloat16* __restrict__ Bm,
                                                 void* __restrict__ Dv) {
  __shared__ __align__(1024) __hip_bfloat16 Ash[128 * 32];
  __shared__ __align__(1024) __hip_bfloat16 Bsh[128 * 32];
  const int m0 = blockIdx.x * 128, n0 = blockIdx.y * 128;
  const int tid = threadIdx.x;
  const int w = tid >> 6, l = tid & 63;
  const int wr = w >> 1, wc = w & 1;
  f32x4 acc[4][4] = {};
  for (int kt = 0; kt < KDIM / 32; ++kt) {
#pragma unroll
    for (int q2 = 0; q2 < 2; ++q2) {
      int c = w * 2 + q2;
      gload_lds16(
          (const char*)A + ((size_t)(m0 + 16 * c + (l >> 2)) * KDIM + (size_t)kt * 32 + (l & 3) * 8) * 2,
          (char*)Ash + c * 1024);
      gload_lds16(
          (const char*)Bm + ((size_t)(n0 + 16 * c + (l >> 2)) * KDIM + (size_t)kt * 32 + (l & 3) * 8) * 2,
          (char*)Bsh + c * 1024);
    }
    __syncthreads();
    const char* Ab = (const char*)Ash + (wr * 64 + (l & 15)) * 64 + (l >> 4) * 16;
    const char* Bb = (const char*)Bsh + (wc * 64 + (l & 15)) * 64 + (l >> 4) * 16;
    bf16x8 af[4], bfv[4];
#pragma unroll
    for (int mi = 0; mi < 4; ++mi) af[mi] = *(const bf16x8*)(Ab + mi * 16 * 64);
#pragma unroll
    for (int ni = 0; ni < 4; ++ni) bfv[ni] = *(const bf16x8*)(Bb + ni * 16 * 64);
#pragma unroll
    for (int mi = 0; mi < 4; ++mi)
#pragma unroll
      for (int ni = 0; ni < 4; ++ni)
        acc[mi][ni] = __builtin_amdgcn_mfma_f32_16x16x32_bf16(af[mi], bfv[ni], acc[mi][ni], 0, 0, 0);
    __syncthreads();
  }
#pragma unroll
  for (int mi = 0; mi < 4; ++mi) {
    int mrow = m0 + wr * 64 + mi * 16 + (l >> 4) * 4;
#pragma unroll
    for (int ni = 0; ni < 4; ++ni) {
      int ncol = n0 + wc * 64 + ni * 16 + (l & 15);
#pragma unroll
      for (int r = 0; r < 4; ++r) {
        if constexpr (OUT_BF16) {
          ((__hip_bfloat16*)Dv)[(size_t)(mrow + r) * NCOL + ncol] =
              __float2bfloat16(acc[mi][ni][r]);
        } else {
          ((float*)Dv)[(size_t)(mrow + r) * NCOL + ncol] = acc[mi][ni][r];
        }
      }
    }
  }
}

// ---------------- row softmax over 2304 keys -> bf16 ----------------
__global__ __launch_bounds__(256) void k_softmax(const float* __restrict__ scT,
                                                 __hip_bfloat16* __restrict__ attT) {
  int p = blockIdx.x;
  int tid = threadIdx.x;
  const float* row = scT + (size_t)p * NKEY;
  float v[9];
  float mx = -1e30f;
#pragma unroll
  for (int t = 0; t < 9; ++t) {
    v[t] = row[tid + t * 256];
    mx = fmaxf(mx, v[t]);
  }
  for (int off = 32; off; off >>= 1) mx = fmaxf(mx, __shfl_xor(mx, off));
  __shared__ float red[4];
  __shared__ float red2[4];
  if ((tid & 63) == 0) red[tid >> 6] = mx;
  __syncthreads();
  mx = fmaxf(fmaxf(red[0], red[1]), fmaxf(red[2], red[3]));
  float s = 0.f;
#pragma unroll
  for (int t = 0; t < 9; ++t) {
    v[t] = __expf(v[t] - mx);
    s += v[t];
  }
  for (int off = 32; off; off >>= 1) s += __shfl_xor(s, off);
  if ((tid & 63) == 0) red2[tid >> 6] = s;
  __syncthreads();
  s = red2[0] + red2[1] + red2[2] + red2[3];
  float inv = 1.f / s;
#pragma unroll
  for (int t = 0; t < 9; ++t)
    attT[(size_t)p * NKEY + tid + t * 256] = __float2bfloat16(v[t] * inv);
}

// ---- build value patches apT[col][n], col=(i*6+j)*64+o; 4 keys/thread ------
__global__ __launch_bounds__(256) void k_apT(const float* __restrict__ asmb,
                                             __hip_bfloat16* __restrict__ apT) {
  int idx = blockIdx.x * 256 + threadIdx.x;
  if (idx >= NCOL * (NKEY / 4)) return;
  int n4 = idx % (NKEY / 4);
  int col = idx / (NKEY / 4);
  int n = n4 * 4;
  int o = col & 63;
  int ij = col >> 6;
  int i = ij / 6, j = ij % 6;
  int ky = n / WD, kx0 = n % WD;   // 4 | WD so all 4 keys share ky
  int y = 2 * ky + i - 2;
  s16x4 outv = {0, 0, 0, 0};
  if ((unsigned)y < (unsigned)HH) {
    const float* rowp = asmb + (size_t)o * HWQ + (size_t)y * WW;
#pragma unroll
    for (int t = 0; t < 4; ++t) {
      int x = 2 * (kx0 + t) + j - 2;
      float v = ((unsigned)x < (unsigned)WW) ? rowp[x] : 0.f;
      __hip_bfloat16 hv = __float2bfloat16(v);
      outv[t] = *reinterpret_cast<short*>(&hv);
    }
  }
  *reinterpret_cast<s16x4*>(apT + (size_t)idx * 4) = outv;
}

// ---------------- gather (transposed conv collapse), /6; V is bf16 ----------
__global__ __launch_bounds__(256) void k_gather(const __hip_bfloat16* __restrict__ V,
                                                float* __restrict__ out) {
  int tid = threadIdx.x;
  int o = tid & 63;
  int X = blockIdx.x * 4 + (tid >> 6);
  int Y = blockIdx.y;
  int y0 = (Y >= 3) ? ((Y - 2) >> 1) : 0;
  int y1 = (Y + 2) >> 1;
  if (y1 > HH - 1) y1 = HH - 1;
  int x0 = (X >= 3) ? ((X - 2) >> 1) : 0;
  int x1 = (X + 2) >> 1;
  if (x1 > WW - 1) x1 = WW - 1;
  float acc = 0.f;
  for (int y = y0; y <= y1; ++y) {
    int i = Y - 2 * y + 2;
    for (int x = x0; x <= x1; ++x) {
      int j = X - 2 * x + 2;
      acc += __bfloat162float(V[(size_t)(y * WW + x) * NCOL + (i * 6 + j) * 64 + o]);
    }
  }
  out[(size_t)o * (OH * OW) + Y * OW + X] = acc * (1.f / 6.f);
}

extern "C" void kernel_launch(void* const* d_in, const int* in_sizes, int n_in,
                              void* d_out, int out_size, void* d_ws, size_t ws_size,
                              hipStream_t stream) {
  const float* x  = (const float*)d_in[0];
  const float* wa = (const float*)d_in[1];
  const float* ba = (const float*)d_in[2];
  const float* aa = (const float*)d_in[3];
  const float* w1 = (const float*)d_in[4];
  const float* b1 = (const float*)d_in[5];
  const float* a1 = (const float*)d_in[6];
  const float* w2 = (const float*)d_in[7];
  const float* b2 = (const float*)d_in[8];
  const float* a2 = (const float*)d_in[9];
  float* out = (float*)d_out;

  char* ws = (char*)d_ws;
  size_t off = 0;
  auto alloc = [&](size_t bytes) {
    char* p = ws + off;
    off += (bytes + 255) & ~(size_t)255;
    return p;
  };
  float* asm_b  = (float*)alloc((size_t)BN * CC * HWQ * 4);   // 9.4 MB
  float* q_b    = (float*)alloc((size_t)BN * CR * HWQ * 4);   // 2.4 MB
  float* xd_b   = (float*)alloc((size_t)BN * CC * HWD * 4);   // 2.4 MB
  float* kf_b   = (float*)alloc((size_t)BN * CR * HWD * 4);   // 0.6 MB
  float* rn_b   = (float*)alloc((size_t)BN * NKEY * 4);
  __hip_bfloat16* qpm2_b = (__hip_bfloat16*)alloc((size_t)HWQ * KSC * 2);   // 8.3 MB
  __hip_bfloat16* kpm2_b = (__hip_bfloat16*)alloc((size_t)NKEY * KSC * 2);  // 2.1 MB
  float* scV_b  = (float*)alloc((size_t)HWQ * NKEY * 4);      // 85 MB (scores f32; V bf16 aliases)
  __hip_bfloat16* attT_b = (__hip_bfloat16*)alloc((size_t)HWQ * NKEY * 2);  // 42.5 MB
  __hip_bfloat16* apT_b  = (__hip_bfloat16*)alloc((size_t)NCOL * NKEY * 2); // 10.6 MB
  __hip_bfloat16* V_b = (__hip_bfloat16*)scV_b;  // V (bf16, 42.5 MB) aliases scores buffer

  // shared preprocessing (all samples at once)
  k_conv1x1_prelu<<<dim3(HWQ / 256, CC, BN), 256, 0, stream>>>(x, wa, ba, aa, asm_b, CC, HWQ);
  k_conv1x1_prelu<<<dim3(HWQ / 256, CR, BN), 256, 0, stream>>>(x, w1, b1, a1, q_b, CR, HWQ);
  k_downsample<<<(BN * CC * HWD + 255) / 256, 256, 0, stream>>>(x, xd_b);
  k_conv1x1_prelu<<<dim3(HWD / 256, CR, BN), 256, 0, stream>>>(xd_b, w2, b2, a2, kf_b, CR, HWD);
  k_rnorm<<<(BN * NKEY + 255) / 256, 256, 0, stream>>>(kf_b, rn_b);

  for (int b = 0; b < BN; ++b) {
    const float* qb   = q_b  + (size_t)b * CR * HWQ;
    const float* kfb  = kf_b + (size_t)b * CR * HWD;
    const float* rnb  = rn_b + (size_t)b * NKEY;
    const float* asmb = asm_b + (size_t)b * CC * HWQ;
    float* outb = out + (size_t)b * CC * OH * OW;

    k_qpm2<<<(HWQ * KPATCH + 255) / 256, 256, 0, stream>>>(qb, qpm2_b);
    k_kpm2<<<(NKEY * KPATCH + 255) / 256, 256, 0, stream>>>(kfb, rnb, kpm2_b);
    k_gemm_bt<KSC, false><<<dim3(HWQ / 128, NKEY / 128), 256, 0, stream>>>(qpm2_b, kpm2_b, scV_b);
    k_softmax<<<HWQ, 256, 0, stream>>>(scV_b, attT_b);
    k_apT<<<(NCOL * (NKEY / 4) + 255) / 256, 256, 0, stream>>>(asmb, apT_b);
    k_gemm_bt<NKEY, true><<<dim3(HWQ / 128, NCOL / 128), 256, 0, stream>>>(attT_b, apT_b, V_b);
    k_gather<<<dim3(OW / 4, OH), 256, 0, stream>>>(V_b, outb);
  }
}

// Round 14
// 1032.796 us; speedup vs baseline: 1.5025x; 1.0085x over previous
//
#include <hip/hip_runtime.h>
#include <hip/hip_bf16.h>

#define BN 4
#define CC 64
#define CR 16
#define HH 96
#define WW 96
#define HWQ (HH*WW)          // 9216
#define HD 48
#define WD 48
#define HWD (HD*WD)          // 2304
#define NKEY 2304
#define KPATCH 144
#define KSC 448              // split-K' = 3*144 padded to 448 (mult of 64)
#define NCOL 2304            // 36*64
#define OH 192
#define OW 192

typedef __bf16 bf16x8 __attribute__((ext_vector_type(8)));
typedef float f32x4 __attribute__((ext_vector_type(4)));
typedef short s16x4 __attribute__((ext_vector_type(4)));

__device__ __forceinline__ void gload_lds16(const void* g, void* l) {
  __builtin_amdgcn_global_load_lds((__attribute__((address_space(1))) void*)g,
                                   (__attribute__((address_space(3))) void*)l,
                                   16, 0, 0);
}

// ---------------- conv1x1 + prelu ----------------
__global__ __launch_bounds__(256) void k_conv1x1_prelu(
    const float* __restrict__ x, const float* __restrict__ w,
    const float* __restrict__ bias, const float* __restrict__ alpha,
    float* __restrict__ out, int O, int HW) {
  int p = blockIdx.x * 256 + threadIdx.x;
  int o = blockIdx.y;
  int b = blockIdx.z;
  if (p >= HW) return;
  const float* xb = x + (size_t)b * CC * HW + p;
  const float* wr = w + o * CC;
  float acc = bias[o];
#pragma unroll 8
  for (int c = 0; c < CC; ++c) acc = fmaf(wr[c], xb[(size_t)c * HW], acc);
  float a = alpha[0];
  out[((size_t)(b * O + o)) * HW + p] = acc >= 0.f ? acc : a * acc;
}

// ---------------- 2x bilinear downsample (== 2x2 average) ----------------
__global__ __launch_bounds__(256) void k_downsample(const float* __restrict__ x,
                                                    float* __restrict__ xd) {
  int idx = blockIdx.x * 256 + threadIdx.x;
  if (idx >= BN * CC * HWD) return;
  int j = idx % WD;
  int t = idx / WD;
  int i = t % HD;
  int bc = t / HD;
  const float* src = x + (size_t)bc * HWQ + (2 * i) * WW + 2 * j;
  xd[idx] = 0.25f * (src[0] + src[1] + src[WW] + src[WW + 1]);
}

// ---------------- per-key reciprocal norms (x10 softmax scale folded) -------
__global__ __launch_bounds__(256) void k_rnorm(const float* __restrict__ kf,
                                               float* __restrict__ rnorm) {
  int idx = blockIdx.x * 256 + threadIdx.x;
  if (idx >= BN * NKEY) return;
  int n = idx % NKEY;
  int b = idx / NKEY;
  int ky = n / WD, kx = n % WD;
  float ss = 0.f;
  for (int c = 0; c < CR; ++c) {
    const float* base = kf + (size_t)(b * CR + c) * HWD;
    for (int i = 0; i < 3; ++i) {
      int y = ky + i - 1;
      if ((unsigned)y >= (unsigned)HD) continue;
      for (int j = 0; j < 3; ++j) {
        int xx = kx + j - 1;
        if ((unsigned)xx >= (unsigned)WD) continue;
        float v = base[y * WD + xx];
        ss += v * v;
      }
    }
  }
  float nrm = fmaxf(sqrtf(ss), 1e-4f);
  rnorm[idx] = 10.f / nrm;
}

// ---- build bf16 hi/lo split query patches: [HWQ][KSC]
// layout per row: [0,144)=hi, [144,288)=lo, [288,432)=hi, [432,448)=0
__global__ __launch_bounds__(256) void k_qpm2(const float* __restrict__ q,
                                              __hip_bfloat16* __restrict__ qpm2) {
  int idx = blockIdx.x * 256 + threadIdx.x;
  if (idx >= HWQ * KPATCH) return;
  int k = idx % KPATCH;
  int p = idx / KPATCH;
  int c = k / 9, r = k % 9;
  int i = r / 3, j = r % 3;
  int y = p / WW, x = p % WW;
  int yy = y + i - 1, xx = x + j - 1;
  float v = 0.f;
  if ((unsigned)yy < (unsigned)HH && (unsigned)xx < (unsigned)WW)
    v = q[(size_t)c * HWQ + yy * WW + xx];
  __hip_bfloat16 hi = __float2bfloat16(v);
  __hip_bfloat16 lo = __float2bfloat16(v - __bfloat162float(hi));
  __hip_bfloat16* row = qpm2 + (size_t)p * KSC;
  row[k] = hi;
  row[KPATCH + k] = lo;
  row[2 * KPATCH + k] = hi;
  if (k < KSC - 3 * KPATCH) row[3 * KPATCH + k] = __float2bfloat16(0.f);
}

// ---- build bf16 hi/lo split key patches scaled by 10/norm: [NKEY][KSC]
// layout per row: [0,144)=hi, [144,288)=hi, [288,432)=lo, [432,448)=0
__global__ __launch_bounds__(256) void k_kpm2(const float* __restrict__ kf,
                                              const float* __restrict__ rn,
                                              __hip_bfloat16* __restrict__ kpm2) {
  int idx = blockIdx.x * 256 + threadIdx.x;
  if (idx >= NKEY * KPATCH) return;
  int k = idx % KPATCH;
  int n = idx / KPATCH;
  int c = k / 9, r = k % 9;
  int i = r / 3, j = r % 3;
  int ky = n / WD, kx = n % WD;
  int yy = ky + i - 1, xx = kx + j - 1;
  float v = 0.f;
  if ((unsigned)yy < (unsigned)HD && (unsigned)xx < (unsigned)WD)
    v = kf[(size_t)c * HWD + yy * WD + xx];
  v *= rn[n];
  __hip_bfloat16 hi = __float2bfloat16(v);
  __hip_bfloat16 lo = __float2bfloat16(v - __bfloat162float(hi));
  __hip_bfloat16* row = kpm2 + (size_t)n * KSC;
  row[k] = hi;
  row[KPATCH + k] = hi;
  row[2 * KPATCH + k] = lo;
  if (k < KSC - 3 * KPATCH) row[3 * KPATCH + k] = __float2bfloat16(0.f);
}

// ---------------- bf16 MFMA GEMM (B^T): D[m][n] = sum_k A[m][k] B[n][k] -----
// K-unrolled x2: stage two 32-wide K-slices into separate LDS buffer pairs
// behind ONE barrier pair per 64-K iteration (halves barrier count; keeps the
// proven [128][32] 64B-row layout so bank-conflict profile is unchanged).
// OUT_BF16: write D as bf16 (AV path) else f32 (scores path)
template <int KDIM, bool OUT_BF16>
__global__ __launch_bounds__(256) void k_gemm_bt(const __hip_bfloat16* __restrict__ A,
                                                 const __hip_bfloat16* __restrict__ Bm,
                                                 void* __restrict__ Dv) {
  __shared__ __align__(1024) __hip_bfloat16 Ash[2][128 * 32];
  __shared__ __align__(1024) __hip_bfloat16 Bsh[2][128 * 32];
  const int m0 = blockIdx.x * 128, n0 = blockIdx.y * 128;
  const int tid = threadIdx.x;
  const int w = tid >> 6, l = tid & 63;
  const int wr = w >> 1, wc = w & 1;
  f32x4 acc[4][4] = {};
  for (int kt = 0; kt < KDIM / 64; ++kt) {
#pragma unroll
    for (int s = 0; s < 2; ++s) {
      int k0 = kt * 64 + s * 32;   // element offset of this 32-wide K-slice
#pragma unroll
      for (int q2 = 0; q2 < 2; ++q2) {
        int c = w * 2 + q2;
        gload_lds16(
            (const char*)A + ((size_t)(m0 + 16 * c + (l >> 2)) * KDIM + k0 + (l & 3) * 8) * 2,
            (char*)Ash[s] + c * 1024);
        gload_lds16(
            (const char*)Bm + ((size_t)(n0 + 16 * c + (l >> 2)) * KDIM + k0 + (l & 3) * 8) * 2,
            (char*)Bsh[s] + c * 1024);
      }
    }
    __syncthreads();
#pragma unroll
    for (int s = 0; s < 2; ++s) {
      const char* Ab = (const char*)Ash[s] + (wr * 64 + (l & 15)) * 64 + (l >> 4) * 16;
      const char* Bb = (const char*)Bsh[s] + (wc * 64 + (l & 15)) * 64 + (l >> 4) * 16;
      bf16x8 af[4], bfv[4];
#pragma unroll
      for (int mi = 0; mi < 4; ++mi) af[mi] = *(const bf16x8*)(Ab + mi * 16 * 64);
#pragma unroll
      for (int ni = 0; ni < 4; ++ni) bfv[ni] = *(const bf16x8*)(Bb + ni * 16 * 64);
#pragma unroll
      for (int mi = 0; mi < 4; ++mi)
#pragma unroll
        for (int ni = 0; ni < 4; ++ni)
          acc[mi][ni] = __builtin_amdgcn_mfma_f32_16x16x32_bf16(af[mi], bfv[ni], acc[mi][ni], 0, 0, 0);
    }
    __syncthreads();
  }
#pragma unroll
  for (int mi = 0; mi < 4; ++mi) {
    int mrow = m0 + wr * 64 + mi * 16 + (l >> 4) * 4;
#pragma unroll
    for (int ni = 0; ni < 4; ++ni) {
      int ncol = n0 + wc * 64 + ni * 16 + (l & 15);
#pragma unroll
      for (int r = 0; r < 4; ++r) {
        if constexpr (OUT_BF16) {
          ((__hip_bfloat16*)Dv)[(size_t)(mrow + r) * NCOL + ncol] =
              __float2bfloat16(acc[mi][ni][r]);
        } else {
          ((float*)Dv)[(size_t)(mrow + r) * NCOL + ncol] = acc[mi][ni][r];
        }
      }
    }
  }
}

// ---------------- row softmax over 2304 keys -> bf16 ----------------
__global__ __launch_bounds__(256) void k_softmax(const float* __restrict__ scT,
                                                 __hip_bfloat16* __restrict__ attT) {
  int p = blockIdx.x;
  int tid = threadIdx.x;
  const float* row = scT + (size_t)p * NKEY;
  float v[9];
  float mx = -1e30f;
#pragma unroll
  for (int t = 0; t < 9; ++t) {
    v[t] = row[tid + t * 256];
    mx = fmaxf(mx, v[t]);
  }
  for (int off = 32; off; off >>= 1) mx = fmaxf(mx, __shfl_xor(mx, off));
  __shared__ float red[4];
  __shared__ float red2[4];
  if ((tid & 63) == 0) red[tid >> 6] = mx;
  __syncthreads();
  mx = fmaxf(fmaxf(red[0], red[1]), fmaxf(red[2], red[3]));
  float s = 0.f;
#pragma unroll
  for (int t = 0; t < 9; ++t) {
    v[t] = __expf(v[t] - mx);
    s += v[t];
  }
  for (int off = 32; off; off >>= 1) s += __shfl_xor(s, off);
  if ((tid & 63) == 0) red2[tid >> 6] = s;
  __syncthreads();
  s = red2[0] + red2[1] + red2[2] + red2[3];
  float inv = 1.f / s;
#pragma unroll
  for (int t = 0; t < 9; ++t)
    attT[(size_t)p * NKEY + tid + t * 256] = __float2bfloat16(v[t] * inv);
}

// ---- build value patches apT[col][n], col=(i*6+j)*64+o; 4 keys/thread ------
__global__ __launch_bounds__(256) void k_apT(const float* __restrict__ asmb,
                                             __hip_bfloat16* __restrict__ apT) {
  int idx = blockIdx.x * 256 + threadIdx.x;
  if (idx >= NCOL * (NKEY / 4)) return;
  int n4 = idx % (NKEY / 4);
  int col = idx / (NKEY / 4);
  int n = n4 * 4;
  int o = col & 63;
  int ij = col >> 6;
  int i = ij / 6, j = ij % 6;
  int ky = n / WD, kx0 = n % WD;   // 4 | WD so all 4 keys share ky
  int y = 2 * ky + i - 2;
  s16x4 outv = {0, 0, 0, 0};
  if ((unsigned)y < (unsigned)HH) {
    const float* rowp = asmb + (size_t)o * HWQ + (size_t)y * WW;
#pragma unroll
    for (int t = 0; t < 4; ++t) {
      int x = 2 * (kx0 + t) + j - 2;
      float v = ((unsigned)x < (unsigned)WW) ? rowp[x] : 0.f;
      __hip_bfloat16 hv = __float2bfloat16(v);
      outv[t] = *reinterpret_cast<short*>(&hv);
    }
  }
  *reinterpret_cast<s16x4*>(apT + (size_t)idx * 4) = outv;
}

// ---------------- gather (transposed conv collapse), /6; V is bf16 ----------
__global__ __launch_bounds__(256) void k_gather(const __hip_bfloat16* __restrict__ V,
                                                float* __restrict__ out) {
  int tid = threadIdx.x;
  int o = tid & 63;
  int X = blockIdx.x * 4 + (tid >> 6);
  int Y = blockIdx.y;
  int y0 = (Y >= 3) ? ((Y - 2) >> 1) : 0;
  int y1 = (Y + 2) >> 1;
  if (y1 > HH - 1) y1 = HH - 1;
  int x0 = (X >= 3) ? ((X - 2) >> 1) : 0;
  int x1 = (X + 2) >> 1;
  if (x1 > WW - 1) x1 = WW - 1;
  float acc = 0.f;
  for (int y = y0; y <= y1; ++y) {
    int i = Y - 2 * y + 2;
    for (int x = x0; x <= x1; ++x) {
      int j = X - 2 * x + 2;
      acc += __bfloat162float(V[(size_t)(y * WW + x) * NCOL + (i * 6 + j) * 64 + o]);
    }
  }
  out[(size_t)o * (OH * OW) + Y * OW + X] = acc * (1.f / 6.f);
}

extern "C" void kernel_launch(void* const* d_in, const int* in_sizes, int n_in,
                              void* d_out, int out_size, void* d_ws, size_t ws_size,
                              hipStream_t stream) {
  const float* x  = (const float*)d_in[0];
  const float* wa = (const float*)d_in[1];
  const float* ba = (const float*)d_in[2];
  const float* aa = (const float*)d_in[3];
  const float* w1 = (const float*)d_in[4];
  const float* b1 = (const float*)d_in[5];
  const float* a1 = (const float*)d_in[6];
  const float* w2 = (const float*)d_in[7];
  const float* b2 = (const float*)d_in[8];
  const float* a2 = (const float*)d_in[9];
  float* out = (float*)d_out;

  char* ws = (char*)d_ws;
  size_t off = 0;
  auto alloc = [&](size_t bytes) {
    char* p = ws + off;
    off += (bytes + 255) & ~(size_t)255;
    return p;
  };
  float* asm_b  = (float*)alloc((size_t)BN * CC * HWQ * 4);   // 9.4 MB
  float* q_b    = (float*)alloc((size_t)BN * CR * HWQ * 4);   // 2.4 MB
  float* xd_b   = (float*)alloc((size_t)BN * CC * HWD * 4);   // 2.4 MB
  float* kf_b   = (float*)alloc((size_t)BN * CR * HWD * 4);   // 0.6 MB
  float* rn_b   = (float*)alloc((size_t)BN * NKEY * 4);
  __hip_bfloat16* qpm2_b = (__hip_bfloat16*)alloc((size_t)HWQ * KSC * 2);   // 8.3 MB
  __hip_bfloat16* kpm2_b = (__hip_bfloat16*)alloc((size_t)NKEY * KSC * 2);  // 2.1 MB
  float* scV_b  = (float*)alloc((size_t)HWQ * NKEY * 4);      // 85 MB (scores f32; V bf16 aliases)
  __hip_bfloat16* attT_b = (__hip_bfloat16*)alloc((size_t)HWQ * NKEY * 2);  // 42.5 MB
  __hip_bfloat16* apT_b  = (__hip_bfloat16*)alloc((size_t)NCOL * NKEY * 2); // 10.6 MB
  __hip_bfloat16* V_b = (__hip_bfloat16*)scV_b;  // V (bf16, 42.5 MB) aliases scores buffer

  // shared preprocessing (all samples at once)
  k_conv1x1_prelu<<<dim3(HWQ / 256, CC, BN), 256, 0, stream>>>(x, wa, ba, aa, asm_b, CC, HWQ);
  k_conv1x1_prelu<<<dim3(HWQ / 256, CR, BN), 256, 0, stream>>>(x, w1, b1, a1, q_b, CR, HWQ);
  k_downsample<<<(BN * CC * HWD + 255) / 256, 256, 0, stream>>>(x, xd_b);
  k_conv1x1_prelu<<<dim3(HWD / 256, CR, BN), 256, 0, stream>>>(xd_b, w2, b2, a2, kf_b, CR, HWD);
  k_rnorm<<<(BN * NKEY + 255) / 256, 256, 0, stream>>>(kf_b, rn_b);

  for (int b = 0; b < BN; ++b) {
    const float* qb   = q_b  + (size_t)b * CR * HWQ;
    const float* kfb  = kf_b + (size_t)b * CR * HWD;
    const float* rnb  = rn_b + (size_t)b * NKEY;
    const float* asmb = asm_b + (size_t)b * CC * HWQ;
    float* outb = out + (size_t)b * CC * OH * OW;

    k_qpm2<<<(HWQ * KPATCH + 255) / 256, 256, 0, stream>>>(qb, qpm2_b);
    k_kpm2<<<(NKEY * KPATCH + 255) / 256, 256, 0, stream>>>(kfb, rnb, kpm2_b);
    k_gemm_bt<KSC, false><<<dim3(HWQ / 128, NKEY / 128), 256, 0, stream>>>(qpm2_b, kpm2_b, scV_b);
    k_softmax<<<HWQ, 256, 0, stream>>>(scV_b, attT_b);
    k_apT<<<(NCOL * (NKEY / 4) + 255) / 256, 256, 0, stream>>>(asmb, apT_b);
    k_gemm_bt<NKEY, true><<<dim3(HWQ / 128, NCOL / 128), 256, 0, stream>>>(attT_b, apT_b, V_b);
    k_gather<<<dim3(OW / 4, OH), 256, 0, stream>>>(V_b, outb);
  }
}